// Round 1
// baseline (100.246 us; speedup 1.0000x reference)
//
#include <hip/hip_runtime.h>

#define NUM_CLASSES 21
#define HW4   65536      // (512*512)/4
#define NGRP  1048576    // 16*512*512/4  (float4 pixel groups)

__global__ __launch_bounds__(256) void iou_hist_kernel(
    const float4* __restrict__ pred, const int4* __restrict__ tgt,
    unsigned int* __restrict__ hist) {
  __shared__ unsigned int sh[3 * NUM_CLASSES];
  const int tid = threadIdx.x;
  if (tid < 3 * NUM_CLASSES) sh[tid] = 0;
  __syncthreads();

  const int lane = tid & 63;
  unsigned int cp = 0, ct = 0, ci = 0;   // lane c owns class c's counts

  const int gstart  = blockIdx.x * blockDim.x + tid;
  const int gstride = gridDim.x * blockDim.x;

  for (int g = gstart; g < NGRP; g += gstride) {
    const int b    = g >> 16;           // batch index (HW/4 = 65536 groups per image)
    const int hw4  = g & (HW4 - 1);
    const int base = b * NUM_CLASSES;

    // argmax over 21 channels, 4 pixels at a time (strict > keeps first max)
    float4 best = pred[(base << 16) + hw4];
    int i0 = 0, i1 = 0, i2 = 0, i3 = 0;
#pragma unroll
    for (int c = 1; c < NUM_CLASSES; ++c) {
      float4 v = pred[((base + c) << 16) + hw4];
      if (v.x > best.x) { best.x = v.x; i0 = c; }
      if (v.y > best.y) { best.y = v.y; i1 = c; }
      if (v.z > best.z) { best.z = v.z; i2 = c; }
      if (v.w > best.w) { best.w = v.w; i3 = c; }
    }

    const int4 t = tgt[g];

    // per-wave ballot histogram: lane c accumulates class c
#pragma unroll
    for (int c = 0; c < NUM_CLASSES; ++c) {
      unsigned int np_ = (unsigned)__popcll(__ballot(i0 == c))
                       + (unsigned)__popcll(__ballot(i1 == c))
                       + (unsigned)__popcll(__ballot(i2 == c))
                       + (unsigned)__popcll(__ballot(i3 == c));
      unsigned int nt_ = (unsigned)__popcll(__ballot(t.x == c))
                       + (unsigned)__popcll(__ballot(t.y == c))
                       + (unsigned)__popcll(__ballot(t.z == c))
                       + (unsigned)__popcll(__ballot(t.w == c));
      unsigned int ni_ = (unsigned)__popcll(__ballot(i0 == c && t.x == c))
                       + (unsigned)__popcll(__ballot(i1 == c && t.y == c))
                       + (unsigned)__popcll(__ballot(i2 == c && t.z == c))
                       + (unsigned)__popcll(__ballot(i3 == c && t.w == c));
      if (lane == c) { cp += np_; ct += nt_; ci += ni_; }
    }
  }

  // wave -> block (LDS), block -> global
  if (lane < NUM_CLASSES) {
    atomicAdd(&sh[lane], cp);
    atomicAdd(&sh[NUM_CLASSES + lane], ct);
    atomicAdd(&sh[2 * NUM_CLASSES + lane], ci);
  }
  __syncthreads();
  if (tid < 3 * NUM_CLASSES) atomicAdd(&hist[tid], sh[tid]);
}

__global__ __launch_bounds__(64) void iou_finalize_kernel(
    const unsigned int* __restrict__ hist, float* __restrict__ out) {
  const int lane = threadIdx.x;
  float iou = 0.0f;
  if (lane < NUM_CLASSES) {
    const float p = (float)hist[lane];
    const float t = (float)hist[NUM_CLASSES + lane];
    const float i = (float)hist[2 * NUM_CLASSES + lane];
    const float u = p + t - i;
    iou = (u > 0.0f) ? (i / (u + 1e-6f)) : 0.0f;
  }
#pragma unroll
  for (int off = 32; off > 0; off >>= 1) iou += __shfl_down(iou, off);
  if (lane == 0) out[0] = iou / (float)NUM_CLASSES;
}

extern "C" void kernel_launch(void* const* d_in, const int* in_sizes, int n_in,
                              void* d_out, int out_size, void* d_ws, size_t ws_size,
                              hipStream_t stream) {
  const float4* pred = (const float4*)d_in[0];
  const int4*   tgt  = (const int4*)d_in[1];
  float*        out  = (float*)d_out;
  unsigned int* hist = (unsigned int*)d_ws;

  // counters must start at zero every call (ws is poisoned once, never re-poisoned)
  hipMemsetAsync(d_ws, 0, 3 * NUM_CLASSES * sizeof(unsigned int), stream);

  iou_hist_kernel<<<2048, 256, 0, stream>>>(pred, tgt, hist);
  iou_finalize_kernel<<<1, 64, 0, stream>>>(hist, out);
}